// Round 6
// baseline (173.122 us; speedup 1.0000x reference)
//
#include <hip/hip_runtime.h>

// VDP dropout:
//   keep      = (u >= 0.1f)
//   mu_out    = mu_in    * keep / 0.9
//   Sigma_out = Sigma_in * keep / 768     (D = last-dim size)
//
// N = 64*197*768 = 9,683,968 fp32. Logical traffic 194 MB/dispatch.
//
// History:
//   R2: 1x float4 grid-stride @2048 blocks, nt stores: 57.8 us/dispatch
//   R4: 2x float4 one-shot, cached stores:             59.6 us/dispatch
//   -> invariant at ~58 us, 2.3 TB/s HBM-visible, VALUBusy 2.2%,
//      occupancy ~58%, VGPR 16 (compiler re-serialized the 6-load MLP).
//      Store cache policy (nt vs cached) proven null (WRITE_SIZE 75.6 MB
//      both ways). Aggregate in-flight bytes/CU already covers the
//      latency-BW product -> NOT an MLP/wave-count problem.
//
// Theory R5/R6 (resubmitted; R5 bench never acquired a GPU): the limiter
// is 5 address streams per wave (copy ubench with 2 streams hits 6.3 TB/s
// at VGPR=8; RMSNorm with 2-3 streams hits 4.9). The only coupling between
// the mu and Sigma paths is the 1-bit keep mask, cheap to recompute from u.
// So: split the grid into two interleaved halves, each a copy-like
// 2-read/1-write pattern:
//   even blocks: u + mu_in    -> mu_out
//   odd  blocks: u + sigma_in -> sigma_out
// u is read twice logically, but the halves are co-scheduled (parity
// interleave) so the second read should hit L2/MALL.

#define DROP_PROP 0.1f

typedef float vfloat4 __attribute__((ext_vector_type(4)));

__global__ __launch_bounds__(256) void vdp_dropout_kernel(
    const vfloat4* __restrict__ mu_in,
    const vfloat4* __restrict__ sigma_in,
    const vfloat4* __restrict__ u,
    vfloat4* __restrict__ mu_out,
    vfloat4* __restrict__ sigma_out,
    int n4)
{
    const int stride = (gridDim.x >> 1) * blockDim.x;
    int i = (blockIdx.x >> 1) * blockDim.x + threadIdx.x;

    if ((blockIdx.x & 1) == 0) {
        // mu path: 2 reads + 1 write per iteration
        const float inv_keep = 1.0f / (1.0f - DROP_PROP);   // 1/0.9
        for (; i < n4; i += stride) {
            vfloat4 uu = u[i];
            vfloat4 m  = mu_in[i];
            vfloat4 r;
            #pragma unroll
            for (int j = 0; j < 4; ++j)
                r[j] = (uu[j] >= DROP_PROP) ? m[j] * inv_keep : 0.0f;
            mu_out[i] = r;
        }
    } else {
        // Sigma path: 2 reads + 1 write per iteration
        const float inv_d = 1.0f / 768.0f;
        for (; i < n4; i += stride) {
            vfloat4 uu = u[i];
            vfloat4 s  = sigma_in[i];
            vfloat4 r;
            #pragma unroll
            for (int j = 0; j < 4; ++j)
                r[j] = (uu[j] >= DROP_PROP) ? s[j] * inv_d : 0.0f;
            sigma_out[i] = r;
        }
    }
}

extern "C" void kernel_launch(void* const* d_in, const int* in_sizes, int n_in,
                              void* d_out, int out_size, void* d_ws, size_t ws_size,
                              hipStream_t stream)
{
    const float* mu_in    = (const float*)d_in[0];
    const float* sigma_in = (const float*)d_in[1];
    const float* u        = (const float*)d_in[2];

    const int n = in_sizes[0];          // 9,683,968
    float* mu_out    = (float*)d_out;           // first n elements
    float* sigma_out = (float*)d_out + n;       // next n elements

    const int n4 = n / 4;               // 2,420,992
    const int block = 256;
    // 2048 blocks per half (8 blocks/CU x 256 CUs), parity-interleaved.
    const int grid = 2 * 2048;

    vdp_dropout_kernel<<<grid, block, 0, stream>>>(
        (const vfloat4*)mu_in, (const vfloat4*)sigma_in, (const vfloat4*)u,
        (vfloat4*)mu_out, (vfloat4*)sigma_out, n4);
}

// Round 7
// 161.247 us; speedup vs baseline: 1.0736x; 1.0736x over previous
//
#include <hip/hip_runtime.h>

// VDP dropout:
//   keep      = (u >= 0.1f)
//   mu_out    = mu_in    * keep / 0.9
//   Sigma_out = Sigma_in * keep / 768     (D = last-dim size)
//
// N = 64*197*768 = 9,683,968 fp32. Logical traffic 194 MB/dispatch.
//
// History (per-dispatch kernel time from rocprof):
//   R2: 1x float4 grid-stride @2048, nt stores:    57.8 us  FETCH 56.7  WRITE 75.6
//   R4: 2x float4 one-shot, cached stores:         59.6 us  FETCH 56.7  WRITE 75.6
//   R6: 2-way stream-split (2-3 streams/wave):     61.5 us  FETCH 75.7  WRITE 75.6
// Invariants: HBM-boundary BW pinned at 2.3-2.5 TB/s in all variants;
// logical service ~3.35 TB/s (L3 serves ~half the reads: FETCH = 49% of
// logical reads in R2 AND R6); all writes reach HBM every dispatch;
// VALU ~3%, occupancy 54-68%, nothing saturated. Kernel-shape levers
// (MLP, stream count, grid) are null within 6%.
//
// R7 probe: PATH lever — full nontemporal streaming (nt loads + nt
// stores) on the best structure (R2). Discriminates:
//   FETCH -> ~113 MB & dur < 48 us : MALL read-mix was the limiter
//   FETCH -> ~113 MB & dur ~ 80 us : MALL was helping; 2.4 TB/s mixed
//                                    HBM ceiling is real
//   FETCH ~ 57 MB    & dur ~ 58 us : nt doesn't control L3 alloc (null);
//                                    next: concurrency shaping

#define DROP_PROP 0.1f

typedef float vfloat4 __attribute__((ext_vector_type(4)));

__global__ __launch_bounds__(256) void vdp_dropout_kernel(
    const vfloat4* __restrict__ mu_in,
    const vfloat4* __restrict__ sigma_in,
    const vfloat4* __restrict__ u,
    vfloat4* __restrict__ mu_out,
    vfloat4* __restrict__ sigma_out,
    int n4)
{
    const float inv_keep = 1.0f / (1.0f - DROP_PROP);   // 1/0.9
    const float inv_d    = 1.0f / 768.0f;

    const int stride = gridDim.x * blockDim.x;

    for (int i = blockIdx.x * blockDim.x + threadIdx.x; i < n4; i += stride) {
        vfloat4 uu = __builtin_nontemporal_load(&u[i]);
        vfloat4 m  = __builtin_nontemporal_load(&mu_in[i]);
        vfloat4 s  = __builtin_nontemporal_load(&sigma_in[i]);

        vfloat4 mo, so;
        #pragma unroll
        for (int j = 0; j < 4; ++j) {
            const bool keep = (uu[j] >= DROP_PROP);
            mo[j] = keep ? m[j] * inv_keep : 0.0f;
            so[j] = keep ? s[j] * inv_d    : 0.0f;
        }

        __builtin_nontemporal_store(mo, &mu_out[i]);
        __builtin_nontemporal_store(so, &sigma_out[i]);
    }
}

extern "C" void kernel_launch(void* const* d_in, const int* in_sizes, int n_in,
                              void* d_out, int out_size, void* d_ws, size_t ws_size,
                              hipStream_t stream)
{
    const float* mu_in    = (const float*)d_in[0];
    const float* sigma_in = (const float*)d_in[1];
    const float* u        = (const float*)d_in[2];

    const int n = in_sizes[0];          // 9,683,968
    float* mu_out    = (float*)d_out;           // first n elements
    float* sigma_out = (float*)d_out + n;       // next n elements

    const int n4 = n / 4;               // 2,420,992
    const int block = 256;
    const int max_blocks = 2048;        // 8 blocks/CU x 256 CUs, one residency round
    int grid = (n4 + block - 1) / block;
    if (grid > max_blocks) grid = max_blocks;

    vdp_dropout_kernel<<<grid, block, 0, stream>>>(
        (const vfloat4*)mu_in, (const vfloat4*)sigma_in, (const vfloat4*)u,
        (vfloat4*)mu_out, (vfloat4*)sigma_out, n4);
}